// Round 1
// 253.044 us; speedup vs baseline: 1.1382x; 1.1382x over previous
//
#include <hip/hip_runtime.h>

#define BB 4
#define LL 2048
#define DD 1024
#define HH 16
#define HD 64

typedef __attribute__((ext_vector_type(8))) short s16x8;
typedef __attribute__((ext_vector_type(4))) short s16x4;
typedef __attribute__((ext_vector_type(4))) float f32x4;

#define SCALE_LOG2E 0.18033688011112042f  // 0.125 * log2(e), folded into Q

__device__ __forceinline__ short f2bf(float f) {
  union { float f; unsigned u; } c;
  c.f = f;
  return (short)((c.u + 0x7fffu + ((c.u >> 16) & 1u)) >> 16);  // RNE
}

// async global -> LDS, 16B per lane. LDS dest = wave-uniform base + lane*16.
__device__ __forceinline__ void cp16(const void* g, void* l) {
  __builtin_amdgcn_global_load_lds(
      (const __attribute__((address_space(1))) void*)g,
      (__attribute__((address_space(3))) void*)l, 16, 0, 0);
}

// ---------------- fp32 -> bf16 convert ----------------
__global__ __launch_bounds__(256) void f2b_kernel(const float* __restrict__ in,
                                                  short* __restrict__ out, int n4) {
  int i = blockIdx.x * blockDim.x + threadIdx.x;
  if (i >= n4) return;
  float4 v = ((const float4*)in)[i];
  s16x4 o;
  o[0] = f2bf(v.x);
  o[1] = f2bf(v.y);
  o[2] = f2bf(v.z);
  o[3] = f2bf(v.w);
  ((s16x4*)out)[i] = o;
}

// ---------------- GEMM: C[M,N] = A[M,K] * B[N,K]^T (bf16 in, MFMA) ----------
// Double-buffered LDS, one barrier/iter. MODE 0: scatter bf16 into Q
// (pre-scaled by SCALE_LOG2E) / K [B,H,L,HD] and V transposed [B,H,HD,L].
// MODE 1: fp32 row-major out.
template <int MODE>
__global__ __launch_bounds__(256) void gemm_bt(const short* __restrict__ A,
                                               const short* __restrict__ Bm,
                                               int K, int N,
                                               short* __restrict__ qo,
                                               short* __restrict__ ko,
                                               short* __restrict__ vo,
                                               float* __restrict__ fo) {
  __shared__ __align__(16) short As[2][128 * 32];
  __shared__ __align__(16) short Bs[2][128 * 32];
  const int tid = threadIdx.x;
  const int m0 = blockIdx.y * 128, n0 = blockIdx.x * 128;
  const int wave = tid >> 6, lane = tid & 63;
  const int quad = lane >> 4, c16 = lane & 15;
  const int wr = (wave >> 1) * 64, wc = (wave & 1) * 64;

  f32x4 zero = {0.f, 0.f, 0.f, 0.f};
  f32x4 acc[4][4];
#pragma unroll
  for (int i = 0; i < 4; i++)
#pragma unroll
    for (int j = 0; j < 4; j++) acc[i][j] = zero;

  const int row1 = tid >> 2, seg = (tid & 3) * 8;  // 64 rows x 4 16B-segments
  const short* Ag = A + (size_t)(m0 + row1) * K + seg;
  const short* Bg = Bm + (size_t)(n0 + row1) * K + seg;

  auto stage = [&](int k0, int bi) {
    cp16(Ag + k0, As[bi] + wave * 512);
    cp16(Ag + (size_t)64 * K + k0, As[bi] + 2048 + wave * 512);
    cp16(Bg + k0, Bs[bi] + wave * 512);
    cp16(Bg + (size_t)64 * K + k0, Bs[bi] + 2048 + wave * 512);
  };

  stage(0, 0);
  __syncthreads();
  const int T = K >> 5;
  for (int t = 0; t < T; t++) {
    if (t + 1 < T) stage((t + 1) * 32, (t + 1) & 1);
    const short* Asb = As[t & 1];
    const short* Bsb = Bs[t & 1];
    s16x8 af[4], bf[4];
#pragma unroll
    for (int i = 0; i < 4; i++)
      af[i] = *(const s16x8*)&Asb[(wr + i * 16 + c16) * 32 + quad * 8];
#pragma unroll
    for (int j = 0; j < 4; j++)
      bf[j] = *(const s16x8*)&Bsb[(wc + j * 16 + c16) * 32 + quad * 8];
#pragma unroll
    for (int i = 0; i < 4; i++)
#pragma unroll
      for (int j = 0; j < 4; j++)
        acc[i][j] = __builtin_amdgcn_mfma_f32_16x16x32_bf16(af[i], bf[j], acc[i][j], 0, 0, 0);
    __syncthreads();  // readers done with buf t; drains t+1 staging
  }

  if (MODE == 0) {
#pragma unroll
    for (int j = 0; j < 4; j++) {
      const int gn = n0 + wc + j * 16 + c16;       // 0..3071
      const int which = gn >> 10;
      const int h = (gn >> 6) & 15;
      const int hd = gn & 63;
      if (which == 2) {
#pragma unroll
        for (int i = 0; i < 4; i++) {
          const int gm = m0 + wr + i * 16 + quad * 4;  // 4 consecutive rows
          const int b = gm >> 11, l = gm & 2047;       // l..l+3 contiguous, 8B-aligned
          s16x4 vv;
#pragma unroll
          for (int r = 0; r < 4; r++) vv[r] = f2bf(acc[i][j][r]);
          *(s16x4*)&vo[((size_t)((b << 4) + h) * HD + hd) * LL + l] = vv;
        }
      } else {
        short* dst = which == 0 ? qo : ko;
        const float sc = which == 0 ? SCALE_LOG2E : 1.0f;  // fold softmax scale into Q
#pragma unroll
        for (int i = 0; i < 4; i++)
#pragma unroll
          for (int r = 0; r < 4; r++) {
            const int gm = m0 + wr + i * 16 + quad * 4 + r;
            const int b = gm >> 11, l = gm & 2047;
            dst[((size_t)((b << 4) + h) * LL + l) * HD + hd] = f2bf(acc[i][j][r] * sc);
          }
      }
    }
  } else {
#pragma unroll
    for (int i = 0; i < 4; i++)
#pragma unroll
      for (int r = 0; r < 4; r++) {
        const int gm = m0 + wr + i * 16 + quad * 4 + r;
#pragma unroll
        for (int j = 0; j < 4; j++) {
          const int gn = n0 + wc + j * 16 + c16;
          fo[(size_t)gm * N + gn] = acc[i][j][r];
        }
      }
  }
}

// ---------------- flash attention: paired q-blocks, 128-key tiles ----------
// Causal load balance: block pi processes q-block (15-pi) then q-block pi —
// exactly 17 tile-rounds per block, grid 8x64 = 512 blocks = 2/CU.
// OCCUPANCY: 8 waves x 16 queries each (was 4 x 32) -> 16 waves/CU = 4/SIMD,
// doubling latency hiding for the serial QK->exp->pack->PV chain. Same LDS
// (64 KB), same staging traffic; LDS read traffic doubles (well under LDS BW).
// S^T = K*Q^T per 16-key block; P in registers; Q pre-scaled; p = 2^s
// (exact after p/l norm); denom via ones-A MFMA on the matrix pipe.
__global__ __launch_bounds__(512, 4) void attn_kernel(const short* __restrict__ Qb,
                                                      const short* __restrict__ Kb,
                                                      const short* __restrict__ Vtb,
                                                      short* __restrict__ Cb) {
  const int pi = blockIdx.x;  // 0..7
  const int bh = blockIdx.y;  // 0..63
  const int tid = threadIdx.x;
  const int wave = tid >> 6, lane = tid & 63;  // wave 0..7
  const int quad = lane >> 4, c16 = lane & 15;
  const int sw = c16 & 7;  // K-read swizzle term
  const size_t base = (size_t)bh * LL * HD;
  const short* Q = Qb + base;
  const short* K = Kb + base;
  const short* Vt = Vtb + base;  // [HD][LL]

  __shared__ __align__(16) short Ks[2][128 * 64];  // [key][hd], 3-bit swizzle
  __shared__ __align__(16) short Vs[2][64 * 128];  // [hd][key], 4-bit swizzle

  const f32x4 zero = {0.f, 0.f, 0.f, 0.f};
  const s16x4 ones = {(short)0x3F80, (short)0x3F80, (short)0x3F80, (short)0x3F80};

  // staging (512 threads): K 2 issues (64 rows x 128B each), V 2 issues
  // (32 rows x 256B each); swizzle terms hoisted (gk&7==k_r, gv&15 const/i).
  const int k_r = lane >> 3, k_c = lane & 7;    // K: 8-row slab, 8 16B granules
  const int v_r = lane >> 4, v_c = lane & 15;   // V: 4-row slab, 16 16B granules
  const int ksw = (k_c ^ k_r) * 8;
  const int vsw = (v_c ^ ((wave * 4 + v_r) & 15)) * 8;
  auto stage = [&](int kb, int bi) {
#pragma unroll
    for (int i = 0; i < 2; i++) {
      const int gk = i * 64 + wave * 8 + k_r;
      cp16(K + (size_t)(kb + gk) * HD + ksw, &Ks[bi][(i * 64 + wave * 8) * 64]);
      const int gv = i * 32 + wave * 4 + v_r;
      cp16(Vt + (size_t)gv * LL + kb + vsw, &Vs[bi][(i * 32 + wave * 4) * 128]);
    }
  };

  // pack 4 f32 -> 4 truncated bf16 via 2 x v_perm_b32
  auto pack4 = [&](const float* p) {
    union { float f; unsigned u; } a0, a1, a2, a3;
    a0.f = p[0]; a1.f = p[1]; a2.f = p[2]; a3.f = p[3];
    union { s16x4 v; unsigned u[2]; } r;
    r.u[0] = __builtin_amdgcn_perm(a1.u, a0.u, 0x07060302u);
    r.u[1] = __builtin_amdgcn_perm(a3.u, a2.u, 0x07060302u);
    return r.v;
  };

  for (int phase = 0; phase < 2; phase++) {
    const int qg = phase == 0 ? (15 - pi) : pi;  // heavy first
    const int qw = qg * 128 + wave * 16;         // this wave's 16 queries
    const int tiles = qg + 1;                    // 128-key tiles

    s16x8 qf[2];
#pragma unroll
    for (int s = 0; s < 2; s++)
      qf[s] = *(const s16x8*)(Q + (size_t)(qw + c16) * HD + s * 32 + quad * 8);

    f32x4 o[4];
#pragma unroll
    for (int j4 = 0; j4 < 4; j4++) o[j4] = zero;
    f32x4 ol = zero;

    stage(0, 0);
    __syncthreads();  // drain tile 0 (also isolates phase 0's last readers)

    for (int t = 0; t < tiles; t++) {
      const int kb = t * 128;
      if (t + 1 < tiles) stage(kb + 128, (t + 1) & 1);
      const short* Kt = &Ks[t & 1][0];
      const short* Vv = &Vs[t & 1][0];

      // causal bounds (wave-uniform): this wave covers queries qw..qw+15
      const int D = qw - kb;                       // >= 0 within tiles range
      const int jm = min((D >> 4) + 1, 8);
      const int jb = D >> 4;

#pragma unroll
      for (int j = 0; j < 8; j++) {
        if (j >= jm) continue;  // wave-uniform skip
        s16x8 kf0 = *(const s16x8*)&Kt[(j * 16 + c16) * 64 + ((quad ^ sw) * 8)];
        s16x8 kf1 = *(const s16x8*)&Kt[(j * 16 + c16) * 64 + (((4 + quad) ^ sw) * 8)];
        s16x4 va[4];
#pragma unroll
        for (int j4 = 0; j4 < 4; j4++)
          va[j4] = *(const s16x4*)&Vv[(j4 * 16 + c16) * 128 +
                                      (((2 * j + (quad >> 1)) ^ c16) * 8) + (quad & 1) * 4];
        f32x4 s = __builtin_amdgcn_mfma_f32_16x16x32_bf16(kf0, qf[0], zero, 0, 0, 0);
        s = __builtin_amdgcn_mfma_f32_16x16x32_bf16(kf1, qf[1], s, 0, 0, 0);
        float p[4];
#pragma unroll
        for (int r = 0; r < 4; r++) p[r] = __builtin_amdgcn_exp2f(s[r]);
        if (j == jb) {
          const int thr = c16 + D - j * 16 - quad * 4;
#pragma unroll
          for (int r = 0; r < 4; r++)
            if (r > thr) p[r] = 0.f;
        }
        s16x4 pb = pack4(p);
        ol = __builtin_amdgcn_mfma_f32_16x16x16bf16_1k(ones, pb, ol, 0, 0, 0);
#pragma unroll
        for (int j4 = 0; j4 < 4; j4++)
          o[j4] = __builtin_amdgcn_mfma_f32_16x16x16bf16_1k(va[j4], pb, o[j4], 0, 0, 0);
      }

      __syncthreads();  // readers done with buf t; drains t+1 staging
    }

    const int b = bh >> 4, h2 = bh & 15;
    const float inv = 1.0f / ol[0];
    const int q = qw + c16;
#pragma unroll
    for (int j4 = 0; j4 < 4; j4++) {
      s16x4 ov;
#pragma unroll
      for (int r = 0; r < 4; r++) ov[r] = f2bf(o[j4][r] * inv);
      *(s16x4*)&Cb[(size_t)(b * LL + q) * DD + h2 * HD + j4 * 16 + quad * 4] = ov;
    }
  }
}

// ---------------- launch ----------------
extern "C" void kernel_launch(void* const* d_in, const int* in_sizes, int n_in,
                              void* d_out, int out_size, void* d_ws, size_t ws_size,
                              hipStream_t stream) {
  const float* x = (const float*)d_in[0];
  const float* wqkv = (const float*)d_in[1];
  const float* wout = (const float*)d_in[2];
  float* out = (float*)d_out;

  const size_t NX = (size_t)BB * LL * DD;  // 8388608
  short* xb = (short*)d_ws;
  short* wqkvb = xb + NX;
  short* woutb = wqkvb + (size_t)3 * DD * DD;
  short* qb = woutb + (size_t)DD * DD;
  short* kb = qb + NX;
  short* vb = kb + NX;   // V transposed: [B,H,HD,L]
  short* cb = vb + NX;
  // total: 92,274,688 bytes of d_ws

  f2b_kernel<<<dim3((unsigned)(NX / 4 / 256)), 256, 0, stream>>>(x, xb, (int)(NX / 4));
  f2b_kernel<<<dim3(3 * DD * DD / 4 / 256), 256, 0, stream>>>(wqkv, wqkvb, 3 * DD * DD / 4);
  f2b_kernel<<<dim3(DD * DD / 4 / 256), 256, 0, stream>>>(wout, woutb, DD * DD / 4);

  gemm_bt<0><<<dim3(3 * DD / 128, BB * LL / 128), 256, 0, stream>>>(
      xb, wqkvb, DD, 3 * DD, qb, kb, vb, nullptr);
  attn_kernel<<<dim3(8, BB * HH), 512, 0, stream>>>(qb, kb, vb, cb);
  gemm_bt<1><<<dim3(DD / 128, BB * LL / 128), 256, 0, stream>>>(
      cb, woutb, DD, DD, nullptr, nullptr, nullptr, out);
}

// Round 2
// 250.763 us; speedup vs baseline: 1.1485x; 1.0091x over previous
//
#include <hip/hip_runtime.h>

#define BB 4
#define LL 2048
#define DD 1024
#define HH 16
#define HD 64

typedef __attribute__((ext_vector_type(8))) short s16x8;
typedef __attribute__((ext_vector_type(4))) short s16x4;
typedef __attribute__((ext_vector_type(4))) float f32x4;

#define SCALE_LOG2E 0.18033688011112042f  // 0.125 * log2(e), folded into Q

__device__ __forceinline__ short f2bf(float f) {
  union { float f; unsigned u; } c;
  c.f = f;
  return (short)((c.u + 0x7fffu + ((c.u >> 16) & 1u)) >> 16);  // RNE
}

// async global -> LDS, 16B per lane. LDS dest = wave-uniform base + lane*16.
__device__ __forceinline__ void cp16(const void* g, void* l) {
  __builtin_amdgcn_global_load_lds(
      (const __attribute__((address_space(1))) void*)g,
      (__attribute__((address_space(3))) void*)l, 16, 0, 0);
}

// ---------------- fp32 -> bf16 convert ----------------
__global__ __launch_bounds__(256) void f2b_kernel(const float* __restrict__ in,
                                                  short* __restrict__ out, int n4) {
  int i = blockIdx.x * blockDim.x + threadIdx.x;
  if (i >= n4) return;
  float4 v = ((const float4*)in)[i];
  s16x4 o;
  o[0] = f2bf(v.x);
  o[1] = f2bf(v.y);
  o[2] = f2bf(v.z);
  o[3] = f2bf(v.w);
  ((s16x4*)out)[i] = o;
}

// ---------------- GEMM: C[M,N] = A[M,K] * B[N,K]^T (bf16 in, MFMA) ----------
// PIPELINE (T3/T4): 4-deep LDS rotation (BK=32 K-tiles), raw s_barrier +
// counted vmcnt. Phase t: ds_read buf[t&3] -> stage K-tile t+3 -> MFMA ->
// vmcnt(8) retires exactly K-tile t+1's 4 loads (8 stay in flight; never
// drain to 0 until the 2-tile tail). Buffer (t+3)&3 was last read in phase
// t-1, whose reads completed before that phase's barrier -> no race.
// SWIZZLE (T2): granule ^= (row>>1)&3 on staged source and LDS read; a wave's
// 256 4B-words then cover all 32 banks exactly 8x (was 4-way conflict).
// MODE 0: scatter bf16 into Q (pre-scaled) / K [B,H,L,HD], V^T [B,H,HD,L].
// MODE 1: fp32 row-major out.
template <int MODE>
__global__ __launch_bounds__(256) void gemm_bt(const short* __restrict__ A,
                                               const short* __restrict__ Bm,
                                               int K, int N,
                                               short* __restrict__ qo,
                                               short* __restrict__ ko,
                                               short* __restrict__ vo,
                                               float* __restrict__ fo) {
  __shared__ __align__(16) short As[4][128 * 32];
  __shared__ __align__(16) short Bs[4][128 * 32];
  const int tid = threadIdx.x;
  const int m0 = blockIdx.y * 128, n0 = blockIdx.x * 128;
  const int wave = tid >> 6, lane = tid & 63;
  const int quad = lane >> 4, c16 = lane & 15;
  const int wr = (wave >> 1) * 64, wc = (wave & 1) * 64;

  f32x4 zero = {0.f, 0.f, 0.f, 0.f};
  f32x4 acc[4][4];
#pragma unroll
  for (int i = 0; i < 4; i++)
#pragma unroll
    for (int j = 0; j < 4; j++) acc[i][j] = zero;

  const int row1 = tid >> 2;                            // 64 rows x 4 16B-granules
  const int gsw = ((tid & 3) ^ ((tid >> 3) & 3)) * 8;   // xor-swizzled src granule
  const short* Ag = A + (size_t)(m0 + row1) * K + gsw;
  const short* Bg = Bm + (size_t)(n0 + row1) * K + gsw;
  const int rsw = (quad ^ ((c16 >> 1) & 3)) * 8;        // xor-swizzled read offset

  auto stage = [&](int t) {
    const int bi = t & 3, k0 = t << 5;
    cp16(Ag + k0, As[bi] + wave * 512);
    cp16(Ag + (size_t)64 * K + k0, As[bi] + 2048 + wave * 512);
    cp16(Bg + k0, Bs[bi] + wave * 512);
    cp16(Bg + (size_t)64 * K + k0, Bs[bi] + 2048 + wave * 512);
  };

  const int T = K >> 5;  // 32 K-tiles at K=1024
  stage(0);
  stage(1);
  stage(2);
  asm volatile("s_waitcnt vmcnt(8)" ::: "memory");  // K-tile 0 resident
  __builtin_amdgcn_s_barrier();
  asm volatile("" ::: "memory");

  for (int t = 0; t < T; t++) {
    const short* Asb = As[t & 3];
    const short* Bsb = Bs[t & 3];
    s16x8 af[4], bfv[4];
#pragma unroll
    for (int i = 0; i < 4; i++)
      af[i] = *(const s16x8*)&Asb[(wr + i * 16 + c16) * 32 + rsw];
#pragma unroll
    for (int j = 0; j < 4; j++)
      bfv[j] = *(const s16x8*)&Bsb[(wc + j * 16 + c16) * 32 + rsw];
    if (t + 3 < T) stage(t + 3);
    __builtin_amdgcn_s_setprio(1);
#pragma unroll
    for (int i = 0; i < 4; i++)
#pragma unroll
      for (int j = 0; j < 4; j++)
        acc[i][j] = __builtin_amdgcn_mfma_f32_16x16x32_bf16(af[i], bfv[j], acc[i][j], 0, 0, 0);
    __builtin_amdgcn_s_setprio(0);
    // retire exactly next K-tile's staging; keep the rest in flight
    if (t < T - 3) asm volatile("s_waitcnt vmcnt(8)" ::: "memory");
    else if (t == T - 3) asm volatile("s_waitcnt vmcnt(4)" ::: "memory");
    else if (t == T - 2) asm volatile("s_waitcnt vmcnt(0)" ::: "memory");
    __builtin_amdgcn_s_barrier();
    asm volatile("" ::: "memory");
  }

  if (MODE == 0) {
#pragma unroll
    for (int j = 0; j < 4; j++) {
      const int gn = n0 + wc + j * 16 + c16;       // 0..3071
      const int which = gn >> 10;
      const int h = (gn >> 6) & 15;
      const int hd = gn & 63;
      if (which == 2) {
#pragma unroll
        for (int i = 0; i < 4; i++) {
          const int gm = m0 + wr + i * 16 + quad * 4;  // 4 consecutive rows
          const int b = gm >> 11, l = gm & 2047;       // l..l+3 contiguous, 8B-aligned
          s16x4 vv;
#pragma unroll
          for (int r = 0; r < 4; r++) vv[r] = f2bf(acc[i][j][r]);
          *(s16x4*)&vo[((size_t)((b << 4) + h) * HD + hd) * LL + l] = vv;
        }
      } else {
        short* dst = which == 0 ? qo : ko;
        const float sc = which == 0 ? SCALE_LOG2E : 1.0f;  // fold softmax scale into Q
#pragma unroll
        for (int i = 0; i < 4; i++)
#pragma unroll
          for (int r = 0; r < 4; r++) {
            const int gm = m0 + wr + i * 16 + quad * 4 + r;
            const int b = gm >> 11, l = gm & 2047;
            dst[((size_t)((b << 4) + h) * LL + l) * HD + hd] = f2bf(acc[i][j][r] * sc);
          }
      }
    }
  } else {
#pragma unroll
    for (int i = 0; i < 4; i++)
#pragma unroll
      for (int r = 0; r < 4; r++) {
        const int gm = m0 + wr + i * 16 + quad * 4 + r;
#pragma unroll
        for (int j = 0; j < 4; j++) {
          const int gn = n0 + wc + j * 16 + c16;
          fo[(size_t)gm * N + gn] = acc[i][j][r];
        }
      }
  }
}

// ---------------- flash attention: paired q-blocks, 128-key tiles ----------
// Causal load balance: block pi processes q-block (15-pi) then q-block pi —
// exactly 17 tile-rounds per block, grid 8x64 = 512 blocks = 2/CU.
// 8 waves x 16 queries each -> 16 waves/CU = 4/SIMD for latency hiding.
// S^T = K*Q^T per 16-key block; P in registers; Q pre-scaled; p = 2^s
// (exact after p/l norm); denom via ones-A MFMA on the matrix pipe.
__global__ __launch_bounds__(512, 4) void attn_kernel(const short* __restrict__ Qb,
                                                      const short* __restrict__ Kb,
                                                      const short* __restrict__ Vtb,
                                                      short* __restrict__ Cb) {
  const int pi = blockIdx.x;  // 0..7
  const int bh = blockIdx.y;  // 0..63
  const int tid = threadIdx.x;
  const int wave = tid >> 6, lane = tid & 63;  // wave 0..7
  const int quad = lane >> 4, c16 = lane & 15;
  const int sw = c16 & 7;  // K-read swizzle term
  const size_t base = (size_t)bh * LL * HD;
  const short* Q = Qb + base;
  const short* K = Kb + base;
  const short* Vt = Vtb + base;  // [HD][LL]

  __shared__ __align__(16) short Ks[2][128 * 64];  // [key][hd], 3-bit swizzle
  __shared__ __align__(16) short Vs[2][64 * 128];  // [hd][key], 4-bit swizzle

  const f32x4 zero = {0.f, 0.f, 0.f, 0.f};
  const s16x4 ones = {(short)0x3F80, (short)0x3F80, (short)0x3F80, (short)0x3F80};

  // staging (512 threads): K 2 issues (64 rows x 128B each), V 2 issues
  // (32 rows x 256B each); swizzle terms hoisted (gk&7==k_r, gv&15 const/i).
  const int k_r = lane >> 3, k_c = lane & 7;    // K: 8-row slab, 8 16B granules
  const int v_r = lane >> 4, v_c = lane & 15;   // V: 4-row slab, 16 16B granules
  const int ksw = (k_c ^ k_r) * 8;
  const int vsw = (v_c ^ ((wave * 4 + v_r) & 15)) * 8;
  auto stage = [&](int kb, int bi) {
#pragma unroll
    for (int i = 0; i < 2; i++) {
      const int gk = i * 64 + wave * 8 + k_r;
      cp16(K + (size_t)(kb + gk) * HD + ksw, &Ks[bi][(i * 64 + wave * 8) * 64]);
      const int gv = i * 32 + wave * 4 + v_r;
      cp16(Vt + (size_t)gv * LL + kb + vsw, &Vs[bi][(i * 32 + wave * 4) * 128]);
    }
  };

  // pack 4 f32 -> 4 truncated bf16 via 2 x v_perm_b32
  auto pack4 = [&](const float* p) {
    union { float f; unsigned u; } a0, a1, a2, a3;
    a0.f = p[0]; a1.f = p[1]; a2.f = p[2]; a3.f = p[3];
    union { s16x4 v; unsigned u[2]; } r;
    r.u[0] = __builtin_amdgcn_perm(a1.u, a0.u, 0x07060302u);
    r.u[1] = __builtin_amdgcn_perm(a3.u, a2.u, 0x07060302u);
    return r.v;
  };

  for (int phase = 0; phase < 2; phase++) {
    const int qg = phase == 0 ? (15 - pi) : pi;  // heavy first
    const int qw = qg * 128 + wave * 16;         // this wave's 16 queries
    const int tiles = qg + 1;                    // 128-key tiles

    s16x8 qf[2];
#pragma unroll
    for (int s = 0; s < 2; s++)
      qf[s] = *(const s16x8*)(Q + (size_t)(qw + c16) * HD + s * 32 + quad * 8);

    f32x4 o[4];
#pragma unroll
    for (int j4 = 0; j4 < 4; j4++) o[j4] = zero;
    f32x4 ol = zero;

    stage(0, 0);
    __syncthreads();  // drain tile 0 (also isolates phase 0's last readers)

    for (int t = 0; t < tiles; t++) {
      const int kb = t * 128;
      if (t + 1 < tiles) stage(kb + 128, (t + 1) & 1);
      const short* Kt = &Ks[t & 1][0];
      const short* Vv = &Vs[t & 1][0];

      // causal bounds (wave-uniform): this wave covers queries qw..qw+15
      const int D = qw - kb;                       // >= 0 within tiles range
      const int jm = min((D >> 4) + 1, 8);
      const int jb = D >> 4;

#pragma unroll
      for (int j = 0; j < 8; j++) {
        if (j >= jm) continue;  // wave-uniform skip
        s16x8 kf0 = *(const s16x8*)&Kt[(j * 16 + c16) * 64 + ((quad ^ sw) * 8)];
        s16x8 kf1 = *(const s16x8*)&Kt[(j * 16 + c16) * 64 + (((4 + quad) ^ sw) * 8)];
        s16x4 va[4];
#pragma unroll
        for (int j4 = 0; j4 < 4; j4++)
          va[j4] = *(const s16x4*)&Vv[(j4 * 16 + c16) * 128 +
                                      (((2 * j + (quad >> 1)) ^ c16) * 8) + (quad & 1) * 4];
        f32x4 s = __builtin_amdgcn_mfma_f32_16x16x32_bf16(kf0, qf[0], zero, 0, 0, 0);
        s = __builtin_amdgcn_mfma_f32_16x16x32_bf16(kf1, qf[1], s, 0, 0, 0);
        float p[4];
#pragma unroll
        for (int r = 0; r < 4; r++) p[r] = __builtin_amdgcn_exp2f(s[r]);
        if (j == jb) {
          const int thr = c16 + D - j * 16 - quad * 4;
#pragma unroll
          for (int r = 0; r < 4; r++)
            if (r > thr) p[r] = 0.f;
        }
        s16x4 pb = pack4(p);
        ol = __builtin_amdgcn_mfma_f32_16x16x16bf16_1k(ones, pb, ol, 0, 0, 0);
#pragma unroll
        for (int j4 = 0; j4 < 4; j4++)
          o[j4] = __builtin_amdgcn_mfma_f32_16x16x16bf16_1k(va[j4], pb, o[j4], 0, 0, 0);
      }

      __syncthreads();  // readers done with buf t; drains t+1 staging
    }

    const int b = bh >> 4, h2 = bh & 15;
    const float inv = 1.0f / ol[0];
    const int q = qw + c16;
#pragma unroll
    for (int j4 = 0; j4 < 4; j4++) {
      s16x4 ov;
#pragma unroll
      for (int r = 0; r < 4; r++) ov[r] = f2bf(o[j4][r] * inv);
      *(s16x4*)&Cb[(size_t)(b * LL + q) * DD + h2 * HD + j4 * 16 + quad * 4] = ov;
    }
  }
}

// ---------------- launch ----------------
extern "C" void kernel_launch(void* const* d_in, const int* in_sizes, int n_in,
                              void* d_out, int out_size, void* d_ws, size_t ws_size,
                              hipStream_t stream) {
  const float* x = (const float*)d_in[0];
  const float* wqkv = (const float*)d_in[1];
  const float* wout = (const float*)d_in[2];
  float* out = (float*)d_out;

  const size_t NX = (size_t)BB * LL * DD;  // 8388608
  short* xb = (short*)d_ws;
  short* wqkvb = xb + NX;
  short* woutb = wqkvb + (size_t)3 * DD * DD;
  short* qb = woutb + (size_t)DD * DD;
  short* kb = qb + NX;
  short* vb = kb + NX;   // V transposed: [B,H,HD,L]
  short* cb = vb + NX;
  // total: 92,274,688 bytes of d_ws

  f2b_kernel<<<dim3((unsigned)(NX / 4 / 256)), 256, 0, stream>>>(x, xb, (int)(NX / 4));
  f2b_kernel<<<dim3(3 * DD * DD / 4 / 256), 256, 0, stream>>>(wqkv, wqkvb, 3 * DD * DD / 4);
  f2b_kernel<<<dim3(DD * DD / 4 / 256), 256, 0, stream>>>(wout, woutb, DD * DD / 4);

  gemm_bt<0><<<dim3(3 * DD / 128, BB * LL / 128), 256, 0, stream>>>(
      xb, wqkvb, DD, 3 * DD, qb, kb, vb, nullptr);
  attn_kernel<<<dim3(8, BB * HH), 512, 0, stream>>>(qb, kb, vb, cb);
  gemm_bt<1><<<dim3(DD / 128, BB * LL / 128), 256, 0, stream>>>(
      cb, woutb, DD, DD, nullptr, nullptr, nullptr, out);
}

// Round 3
// 246.320 us; speedup vs baseline: 1.1692x; 1.0180x over previous
//
#include <hip/hip_runtime.h>

#define BB 4
#define LL 2048
#define DD 1024
#define HH 16
#define HD 64

typedef __attribute__((ext_vector_type(8))) short s16x8;
typedef __attribute__((ext_vector_type(4))) short s16x4;
typedef __attribute__((ext_vector_type(4))) float f32x4;

#define SCALE_LOG2E 0.18033688011112042f  // 0.125 * log2(e), folded into Q

__device__ __forceinline__ short f2bf(float f) {
  union { float f; unsigned u; } c;
  c.f = f;
  return (short)((c.u + 0x7fffu + ((c.u >> 16) & 1u)) >> 16);  // RNE
}

// async global -> LDS, 16B per lane. LDS dest = wave-uniform base + lane*16.
__device__ __forceinline__ void cp16(const void* g, void* l) {
  __builtin_amdgcn_global_load_lds(
      (const __attribute__((address_space(1))) void*)g,
      (__attribute__((address_space(3))) void*)l, 16, 0, 0);
}

template <int N>
__device__ __forceinline__ void waitvm() {
  static_assert(N == 0 || N == 3 || N == 4 || N == 6 || N == 8, "vmcnt imm");
  if constexpr (N == 0) asm volatile("s_waitcnt vmcnt(0)" ::: "memory");
  else if constexpr (N == 3) asm volatile("s_waitcnt vmcnt(3)" ::: "memory");
  else if constexpr (N == 4) asm volatile("s_waitcnt vmcnt(4)" ::: "memory");
  else if constexpr (N == 6) asm volatile("s_waitcnt vmcnt(6)" ::: "memory");
  else if constexpr (N == 8) asm volatile("s_waitcnt vmcnt(8)" ::: "memory");
}

// ---------------- fp32 -> bf16 convert ----------------
__global__ __launch_bounds__(256) void f2b_kernel(const float* __restrict__ in,
                                                  short* __restrict__ out, int n4) {
  int i = blockIdx.x * blockDim.x + threadIdx.x;
  if (i >= n4) return;
  float4 v = ((const float4*)in)[i];
  s16x4 o;
  o[0] = f2bf(v.x);
  o[1] = f2bf(v.y);
  o[2] = f2bf(v.z);
  o[3] = f2bf(v.w);
  ((s16x4*)out)[i] = o;
}

// ---------------- GEMM: C[M,N] = A[M,K] * B[N,K]^T (bf16 in, MFMA) ----------
// 512 threads = 8 waves (2M x 4N); per-wave output (BM/2) x (BN/4).
// BM=BN=256: 32 MFMA per wave per BK=32 step vs 12 ds_read -> 2x the MFMA
// density of the 128^2 tile (which measured MfmaUtil 28% = pure-pipe floor).
// PIPELINE (T3/T4): 4-deep LDS rotation, raw s_barrier + counted vmcnt.
// Phase t: ds_read buf[t&3] -> stage K-tile t+3 -> MFMA -> vmcnt(2L) retires
// exactly K-tile t+1's L loads (2L stay in flight; drain only in 2-tile tail).
// Buffer (t+3)&3 was last read in phase t-1, whose reads are consumed before
// that phase's barrier -> no race.
// SWIZZLE (T2, measured 0 conflicts): granule ^= (row>>1)&3 on staged source
// and LDS read; every 16-lane fragment read lands 2 lanes/bank (free).
// MODE 0: scatter bf16 into Q (pre-scaled) / K [B,H,L,HD], V^T [B,H,HD,L].
// MODE 1: fp32 row-major out.
template <int BM, int BN, int MODE>
__global__ __launch_bounds__(512, 2) void gemm_bt(const short* __restrict__ A,
                                                  const short* __restrict__ Bm,
                                                  int K, int N,
                                                  short* __restrict__ qo,
                                                  short* __restrict__ ko,
                                                  short* __restrict__ vo,
                                                  float* __restrict__ fo) {
  constexpr int MR = BM / 32;        // A-frags per wave
  constexpr int NR = BN / 64;        // B-frags per wave
  constexpr int ABATCH = BM / 128;   // 128-row staging batches of A
  constexpr int BBATCH = BN / 128;   // 128-row staging batches of B
  constexpr int L = (BM + BN) / 128; // cp16 per thread per K-step

  __shared__ __align__(16) short As[4][BM * 32];
  __shared__ __align__(16) short Bs[4][BN * 32];
  const int tid = threadIdx.x;
  const int m0 = blockIdx.y * BM, n0 = blockIdx.x * BN;
  const int wave = tid >> 6, lane = tid & 63;
  const int quad = lane >> 4, c16 = lane & 15;
  const int wr = (wave >> 2) * (BM / 2), wc = (wave & 3) * (BN / 4);

  f32x4 zero = {0.f, 0.f, 0.f, 0.f};
  f32x4 acc[MR][NR];
#pragma unroll
  for (int i = 0; i < MR; i++)
#pragma unroll
    for (int j = 0; j < NR; j++) acc[i][j] = zero;

  const int row_s = tid >> 2;                           // 128 rows x 4 16B-granules
  const int gsw = ((tid & 3) ^ ((tid >> 3) & 3)) * 8;   // xor-swizzled src granule
  const short* Ag = A + (size_t)(m0 + row_s) * K + gsw;
  const short* Bg = Bm + (size_t)(n0 + row_s) * K + gsw;
  const int rsw = (quad ^ ((c16 >> 1) & 3)) * 8;        // xor-swizzled read offset

  auto stage = [&](int t) {
    const int bi = t & 3, k0 = t << 5;
#pragma unroll
    for (int b = 0; b < ABATCH; b++)
      cp16(Ag + (size_t)b * 128 * K + k0, As[bi] + (b * 128 + (wave << 4)) * 32);
#pragma unroll
    for (int b = 0; b < BBATCH; b++)
      cp16(Bg + (size_t)b * 128 * K + k0, Bs[bi] + (b * 128 + (wave << 4)) * 32);
  };

  const int T = K >> 5;  // 32 K-tiles at K=1024
  stage(0);
  stage(1);
  stage(2);
  waitvm<2 * L>();  // K-tile 0 resident
  __builtin_amdgcn_s_barrier();
  asm volatile("" ::: "memory");

  for (int t = 0; t < T; t++) {
    const short* Asb = As[t & 3];
    const short* Bsb = Bs[t & 3];
    s16x8 af[MR], bfv[NR];
#pragma unroll
    for (int i = 0; i < MR; i++)
      af[i] = *(const s16x8*)&Asb[(wr + i * 16 + c16) * 32 + rsw];
#pragma unroll
    for (int j = 0; j < NR; j++)
      bfv[j] = *(const s16x8*)&Bsb[(wc + j * 16 + c16) * 32 + rsw];
    if (t + 3 < T) stage(t + 3);
    __builtin_amdgcn_s_setprio(1);
#pragma unroll
    for (int i = 0; i < MR; i++)
#pragma unroll
      for (int j = 0; j < NR; j++)
        acc[i][j] = __builtin_amdgcn_mfma_f32_16x16x32_bf16(af[i], bfv[j], acc[i][j], 0, 0, 0);
    __builtin_amdgcn_s_setprio(0);
    // retire exactly next K-tile's staging; keep the rest in flight
    if (t < T - 3) waitvm<2 * L>();
    else if (t == T - 3) waitvm<L>();
    else if (t == T - 2) waitvm<0>();
    __builtin_amdgcn_s_barrier();
    asm volatile("" ::: "memory");
  }

  if (MODE == 0) {
#pragma unroll
    for (int j = 0; j < NR; j++) {
      const int gn = n0 + wc + j * 16 + c16;       // 0..3071
      const int which = gn >> 10;
      const int h = (gn >> 6) & 15;
      const int hd = gn & 63;
      if (which == 2) {
#pragma unroll
        for (int i = 0; i < MR; i++) {
          const int gm = m0 + wr + i * 16 + quad * 4;  // 4 consecutive rows
          const int b = gm >> 11, l = gm & 2047;       // l..l+3 contiguous, 8B-aligned
          s16x4 vv;
#pragma unroll
          for (int r = 0; r < 4; r++) vv[r] = f2bf(acc[i][j][r]);
          *(s16x4*)&vo[((size_t)((b << 4) + h) * HD + hd) * LL + l] = vv;
        }
      } else {
        short* dst = which == 0 ? qo : ko;
        const float sc = which == 0 ? SCALE_LOG2E : 1.0f;  // fold softmax scale into Q
#pragma unroll
        for (int i = 0; i < MR; i++)
#pragma unroll
          for (int r = 0; r < 4; r++) {
            const int gm = m0 + wr + i * 16 + quad * 4 + r;
            const int b = gm >> 11, l = gm & 2047;
            dst[((size_t)((b << 4) + h) * LL + l) * HD + hd] = f2bf(acc[i][j][r] * sc);
          }
      }
    }
  } else {
#pragma unroll
    for (int i = 0; i < MR; i++)
#pragma unroll
      for (int r = 0; r < 4; r++) {
        const int gm = m0 + wr + i * 16 + quad * 4 + r;
#pragma unroll
        for (int j = 0; j < NR; j++) {
          const int gn = n0 + wc + j * 16 + c16;
          fo[(size_t)gm * N + gn] = acc[i][j][r];
        }
      }
  }
}

// ---------------- flash attention: paired q-blocks, 128-key tiles ----------
// Causal load balance: block pi processes q-block (15-pi) then q-block pi —
// exactly 17 tile-rounds per block, grid 8x64 = 512 blocks = 2/CU.
// 8 waves x 16 queries each -> 16 waves/CU = 4/SIMD for latency hiding.
// S^T = K*Q^T per 16-key block; P in registers; Q pre-scaled; p = 2^s
// (exact after p/l norm); denom via ones-A MFMA on the matrix pipe.
__global__ __launch_bounds__(512, 4) void attn_kernel(const short* __restrict__ Qb,
                                                      const short* __restrict__ Kb,
                                                      const short* __restrict__ Vtb,
                                                      short* __restrict__ Cb) {
  const int pi = blockIdx.x;  // 0..7
  const int bh = blockIdx.y;  // 0..63
  const int tid = threadIdx.x;
  const int wave = tid >> 6, lane = tid & 63;  // wave 0..7
  const int quad = lane >> 4, c16 = lane & 15;
  const int sw = c16 & 7;  // K-read swizzle term
  const size_t base = (size_t)bh * LL * HD;
  const short* Q = Qb + base;
  const short* K = Kb + base;
  const short* Vt = Vtb + base;  // [HD][LL]

  __shared__ __align__(16) short Ks[2][128 * 64];  // [key][hd], 3-bit swizzle
  __shared__ __align__(16) short Vs[2][64 * 128];  // [hd][key], 4-bit swizzle

  const f32x4 zero = {0.f, 0.f, 0.f, 0.f};
  const s16x4 ones = {(short)0x3F80, (short)0x3F80, (short)0x3F80, (short)0x3F80};

  // staging (512 threads): K 2 issues (64 rows x 128B each), V 2 issues
  // (32 rows x 256B each); swizzle terms hoisted (gk&7==k_r, gv&15 const/i).
  const int k_r = lane >> 3, k_c = lane & 7;    // K: 8-row slab, 8 16B granules
  const int v_r = lane >> 4, v_c = lane & 15;   // V: 4-row slab, 16 16B granules
  const int ksw = (k_c ^ k_r) * 8;
  const int vsw = (v_c ^ ((wave * 4 + v_r) & 15)) * 8;
  auto stage = [&](int kb, int bi) {
#pragma unroll
    for (int i = 0; i < 2; i++) {
      const int gk = i * 64 + wave * 8 + k_r;
      cp16(K + (size_t)(kb + gk) * HD + ksw, &Ks[bi][(i * 64 + wave * 8) * 64]);
      const int gv = i * 32 + wave * 4 + v_r;
      cp16(Vt + (size_t)gv * LL + kb + vsw, &Vs[bi][(i * 32 + wave * 4) * 128]);
    }
  };

  // pack 4 f32 -> 4 truncated bf16 via 2 x v_perm_b32
  auto pack4 = [&](const float* p) {
    union { float f; unsigned u; } a0, a1, a2, a3;
    a0.f = p[0]; a1.f = p[1]; a2.f = p[2]; a3.f = p[3];
    union { s16x4 v; unsigned u[2]; } r;
    r.u[0] = __builtin_amdgcn_perm(a1.u, a0.u, 0x07060302u);
    r.u[1] = __builtin_amdgcn_perm(a3.u, a2.u, 0x07060302u);
    return r.v;
  };

  for (int phase = 0; phase < 2; phase++) {
    const int qg = phase == 0 ? (15 - pi) : pi;  // heavy first
    const int qw = qg * 128 + wave * 16;         // this wave's 16 queries
    const int tiles = qg + 1;                    // 128-key tiles

    s16x8 qf[2];
#pragma unroll
    for (int s = 0; s < 2; s++)
      qf[s] = *(const s16x8*)(Q + (size_t)(qw + c16) * HD + s * 32 + quad * 8);

    f32x4 o[4];
#pragma unroll
    for (int j4 = 0; j4 < 4; j4++) o[j4] = zero;
    f32x4 ol = zero;

    stage(0, 0);
    __syncthreads();  // drain tile 0 (also isolates phase 0's last readers)

    for (int t = 0; t < tiles; t++) {
      const int kb = t * 128;
      if (t + 1 < tiles) stage(kb + 128, (t + 1) & 1);
      const short* Kt = &Ks[t & 1][0];
      const short* Vv = &Vs[t & 1][0];

      // causal bounds (wave-uniform): this wave covers queries qw..qw+15
      const int D = qw - kb;                       // >= 0 within tiles range
      const int jm = min((D >> 4) + 1, 8);
      const int jb = D >> 4;

#pragma unroll
      for (int j = 0; j < 8; j++) {
        if (j >= jm) continue;  // wave-uniform skip
        s16x8 kf0 = *(const s16x8*)&Kt[(j * 16 + c16) * 64 + ((quad ^ sw) * 8)];
        s16x8 kf1 = *(const s16x8*)&Kt[(j * 16 + c16) * 64 + (((4 + quad) ^ sw) * 8)];
        s16x4 va[4];
#pragma unroll
        for (int j4 = 0; j4 < 4; j4++)
          va[j4] = *(const s16x4*)&Vv[(j4 * 16 + c16) * 128 +
                                      (((2 * j + (quad >> 1)) ^ c16) * 8) + (quad & 1) * 4];
        f32x4 s = __builtin_amdgcn_mfma_f32_16x16x32_bf16(kf0, qf[0], zero, 0, 0, 0);
        s = __builtin_amdgcn_mfma_f32_16x16x32_bf16(kf1, qf[1], s, 0, 0, 0);
        float p[4];
#pragma unroll
        for (int r = 0; r < 4; r++) p[r] = __builtin_amdgcn_exp2f(s[r]);
        if (j == jb) {
          const int thr = c16 + D - j * 16 - quad * 4;
#pragma unroll
          for (int r = 0; r < 4; r++)
            if (r > thr) p[r] = 0.f;
        }
        s16x4 pb = pack4(p);
        ol = __builtin_amdgcn_mfma_f32_16x16x16bf16_1k(ones, pb, ol, 0, 0, 0);
#pragma unroll
        for (int j4 = 0; j4 < 4; j4++)
          o[j4] = __builtin_amdgcn_mfma_f32_16x16x16bf16_1k(va[j4], pb, o[j4], 0, 0, 0);
      }

      __syncthreads();  // readers done with buf t; drains t+1 staging
    }

    const int b = bh >> 4, h2 = bh & 15;
    const float inv = 1.0f / ol[0];
    const int q = qw + c16;
#pragma unroll
    for (int j4 = 0; j4 < 4; j4++) {
      s16x4 ov;
#pragma unroll
      for (int r = 0; r < 4; r++) ov[r] = f2bf(o[j4][r] * inv);
      *(s16x4*)&Cb[(size_t)(b * LL + q) * DD + h2 * HD + j4 * 16 + quad * 4] = ov;
    }
  }
}

// ---------------- launch ----------------
extern "C" void kernel_launch(void* const* d_in, const int* in_sizes, int n_in,
                              void* d_out, int out_size, void* d_ws, size_t ws_size,
                              hipStream_t stream) {
  const float* x = (const float*)d_in[0];
  const float* wqkv = (const float*)d_in[1];
  const float* wout = (const float*)d_in[2];
  float* out = (float*)d_out;

  const size_t NX = (size_t)BB * LL * DD;  // 8388608
  short* xb = (short*)d_ws;
  short* wqkvb = xb + NX;
  short* woutb = wqkvb + (size_t)3 * DD * DD;
  short* qb = woutb + (size_t)DD * DD;
  short* kb = qb + NX;
  short* vb = kb + NX;   // V transposed: [B,H,HD,L]
  short* cb = vb + NX;
  // total: 92,274,688 bytes of d_ws

  f2b_kernel<<<dim3((unsigned)(NX / 4 / 256)), 256, 0, stream>>>(x, xb, (int)(NX / 4));
  f2b_kernel<<<dim3(3 * DD * DD / 4 / 256), 256, 0, stream>>>(wqkv, wqkvb, 3 * DD * DD / 4);
  f2b_kernel<<<dim3(DD * DD / 4 / 256), 256, 0, stream>>>(wout, woutb, DD * DD / 4);

  // gemm0: 256^2 tiles -> 12 x 32 = 384 blocks (1 block/CU, 128 KB LDS)
  gemm_bt<256, 256, 0><<<dim3(3 * DD / 256, BB * LL / 256), 512, 0, stream>>>(
      xb, wqkvb, DD, 3 * DD, qb, kb, vb, nullptr);
  attn_kernel<<<dim3(8, BB * HH), 512, 0, stream>>>(qb, kb, vb, cb);
  // gemm1: 128x256 tiles -> 4 x 64 = 256 blocks = one perfectly balanced round
  gemm_bt<128, 256, 1><<<dim3(DD / 256, BB * LL / 128), 512, 0, stream>>>(
      cb, woutb, DD, DD, nullptr, nullptr, nullptr, out);
}